// Round 6
// baseline (257.752 us; speedup 1.0000x reference)
//
#include <hip/hip_runtime.h>

// DropNorm: B=4096 rows, F=8192 features, fp32.
//   n = F/2; mu = sum(x*m)/n; sigma2 = sum(((x-mu)*m)^2)/(n-1)
//   out = gamma*m*(x-mu)*rsqrt(sigma2^2 + 1e-4) + beta   [sigma2 SQUARED: quirk]
//
// R9: split into TWO PURE STREAMING PASSES; L3 carries x between them.
//   R8 post-mortem: counted-vmcnt DMA pipeline fixed traffic (FETCH 66MB,
//   WRITE 131MB) but dur stayed 82.6us. Five fused structures all sit at
//   2.4-3.2 TB/s: the read->reduce->write dependency defeats every schedule.
//   Everything that hits 5-6.8 TB/s on this chip (fill, float4 copy, m146
//   RMSNorm, m219 LN) is a stall-free stream hiding latency with TLP.
//   Fix: dissolve the dependency.
//     pass A (stats): wave-per-row, no LDS, no barriers; 32 dwordx4/lane
//       double-buffered; masked accumulate via packed per-lane mask bits;
//       butterfly reduce; lane0 stores {mu, inv} (8 B/row). Pure read.
//     pass B (apply): block-per-row elementwise out = mg*(x-mu)*inv + beta,
//       NT store. x is L3-resident from pass A (134MB < 256MB L3, NT writes
//       don't allocate) -> B is write-stream-limited, the fill regime.
//   Tripwire: apply's FETCH must be << 134MB, else L3 retention failed.

constexpr int Bn = 4096;
constexpr int Fn = 8192;
constexpr int NT = 256;           // threads per block

typedef float f4 __attribute__((ext_vector_type(4)));

#define EPSV 1e-4f

__device__ inline int nzbytes(unsigned v) {
    return ((v & 0x000000ffu) != 0) + ((v & 0x0000ff00u) != 0) +
           ((v & 0x00ff0000u) != 0) + ((v & 0xff000000u) != 0);
}

// Prep: detect mask storage layout (uint8 bool vs int32), then materialize
//   mg[j]     = mask ? gamma[j] : 0.0                       (Fn floats)
//   lwpk[256] = per-lane packed mask bits for the stats kernel:
//       uint4 word q of lane L, bit (4*(k&7)+j) = mask[4*L + 256*k + j]
//       (feature of lane L, f4-chunk k, component j; k = 8q..8q+7)
// Detection: count nonzero among the first Fn BYTES. uint8 layout -> exactly
// Fn/2 = 4096; int32 layout -> those bytes span only 2048 ints -> count <= 2048.
__global__ __launch_bounds__(NT) void prep_kernel(const void* __restrict__ mask_raw,
                                                  const float* __restrict__ gamma,
                                                  unsigned* __restrict__ lwpk,
                                                  float* __restrict__ mg) {
    const unsigned char* mb = (const unsigned char*)mask_raw;
    const int* mi = (const int*)mask_raw;
    const uint4* mv = (const uint4*)mask_raw;
    const int tid = threadIdx.x;

    int cnt = 0;
#pragma unroll
    for (int k = 0; k < Fn / 16 / NT; ++k) {   // 2 iterations
        const uint4 w = mv[tid + k * NT];
        cnt += nzbytes(w.x) + nzbytes(w.y) + nzbytes(w.z) + nzbytes(w.w);
    }
    for (int off = 32; off > 0; off >>= 1) cnt += __shfl_down(cnt, off, 64);

    __shared__ int wc[NT / 64];
    __shared__ int flag;
    if ((tid & 63) == 0) wc[tid >> 6] = cnt;
    __syncthreads();
    if (tid == 0) {
        int total = wc[0] + wc[1] + wc[2] + wc[3];
        flag = (total == Fn / 2) ? 1 : 0;   // 1 = uint8 layout, 0 = int32 layout
    }
    __syncthreads();
    const bool u8 = (flag != 0);

    const int per_block = Fn / gridDim.x;
    const int base = blockIdx.x * per_block;
    for (int j = base + tid; j < base + per_block; j += NT) {
        const bool on = u8 ? (mb[j] != 0) : (mi[j] != 0);
        mg[j] = on ? gamma[j] : 0.0f;
    }

    // packed per-lane mask words (block 0 only; mask bytes are cache-hot).
    // thread t builds word t: lane = t>>2, q = t&3.
    if (blockIdx.x == 0) {
        const int lane = tid >> 2;
        const int q = tid & 3;
        unsigned w = 0;
#pragma unroll
        for (int b = 0; b < 32; ++b) {
            const int k = 8 * q + (b >> 2);
            const int j = b & 3;
            const int f = 4 * lane + 256 * k + j;
            const bool on = u8 ? (mb[f] != 0) : (mi[f] != 0);
            w |= (on ? 1u : 0u) << b;
        }
        lwpk[tid] = w;
    }
}

// Pass A: wave-per-row masked stats. Pure read stream, no LDS, no barriers.
// Each lane owns 128 features (32 f4 chunks, coalesced, double-buffered x8).
__global__ __launch_bounds__(NT) void stats_kernel(const float* __restrict__ x,
                                                   const unsigned* __restrict__ lwpk,
                                                   float2* __restrict__ stats) {
    const int tid = threadIdx.x;
    const int lane = tid & 63;
    const int row = blockIdx.x * 4 + (tid >> 6);

    const f4* __restrict__ xr = (const f4*)(x + (size_t)row * Fn);
    const uint4 lw = ((const uint4*)lwpk)[lane];   // 16B: mask for 128 features

    float s = 0.f, ss = 0.f;
    f4 xb[2][8];
#pragma unroll
    for (int k = 0; k < 8; ++k) xb[0][k] = xr[lane + 64 * k];
#pragma unroll
    for (int q = 0; q < 4; ++q) {
        if (q < 3) {
#pragma unroll
            for (int k = 0; k < 8; ++k)
                xb[(q + 1) & 1][k] = xr[lane + 64 * ((q + 1) * 8 + k)];
        }
        const unsigned wq = (q == 0) ? lw.x : (q == 1) ? lw.y : (q == 2) ? lw.z : lw.w;
#pragma unroll
        for (int k = 0; k < 8; ++k) {
            const f4 v = xb[q & 1][k];
            const float a0 = ((wq >> (4 * k + 0)) & 1u) ? v.x : 0.f;
            const float a1 = ((wq >> (4 * k + 1)) & 1u) ? v.y : 0.f;
            const float a2 = ((wq >> (4 * k + 2)) & 1u) ? v.z : 0.f;
            const float a3 = ((wq >> (4 * k + 3)) & 1u) ? v.w : 0.f;
            s  += (a0 + a1) + (a2 + a3);
            ss += (a0 * a0 + a1 * a1) + (a2 * a2 + a3 * a3);
        }
    }

    // 64-lane butterfly: every lane gets the row sums; lane 0 stores stats.
    for (int off = 32; off > 0; off >>= 1) {
        s  += __shfl_xor(s, off, 64);
        ss += __shfl_xor(ss, off, 64);
    }
    if (lane == 0) {
        const float n  = (float)(Fn / 2);
        const float mu = s / n;
        // sum(diff^2) = sum(x^2 m) - n*mu^2   (sum(m) == n exactly)
        const float sigma2 = (ss - n * mu * mu) / (n - 1.0f);
        const float inv = rsqrtf(sigma2 * sigma2 + EPSV);  // quirk: sigma2^2
        stats[row] = make_float2(mu, inv);
    }
}

// Pass B: block-per-row pure elementwise apply. x reads are L3 hits (pass A
// just streamed all 134MB through the 256MB Infinity Cache); out via NT
// store (write stream, no L3 allocation). mg==0 on masked-off features ->
// out = beta, matching scatter-into-zeros semantics.
__global__ __launch_bounds__(NT) void apply_kernel(const float* __restrict__ x,
                                                   const float* __restrict__ mg,
                                                   const float* __restrict__ beta,
                                                   const float2* __restrict__ stats,
                                                   float* __restrict__ out) {
    const int tid = threadIdx.x;
    const int row = blockIdx.x;

    const float2 st = stats[row];          // wave-uniform -> scalar load
    const float mu = st.x, inv = st.y;

    const f4* __restrict__ xr = (const f4*)(x + (size_t)row * Fn);
    const f4* __restrict__ g4 = (const f4*)mg;
    const f4* __restrict__ b4 = (const f4*)beta;
    f4* __restrict__ o4       = (f4*)(out + (size_t)row * Fn);

    f4 xv[8], gv[8], bv[8];
#pragma unroll
    for (int k = 0; k < 8; ++k) xv[k] = xr[tid + k * NT];   // L3-hot
#pragma unroll
    for (int k = 0; k < 8; ++k) gv[k] = g4[tid + k * NT];   // L2-hot
#pragma unroll
    for (int k = 0; k < 8; ++k) bv[k] = b4[tid + k * NT];   // L2-hot
#pragma unroll
    for (int k = 0; k < 8; ++k) {
        f4 o;
        o.x = gv[k].x * (xv[k].x - mu) * inv + bv[k].x;
        o.y = gv[k].y * (xv[k].y - mu) * inv + bv[k].y;
        o.z = gv[k].z * (xv[k].z - mu) * inv + bv[k].z;
        o.w = gv[k].w * (xv[k].w - mu) * inv + bv[k].w;
        __builtin_nontemporal_store(o, o4 + tid + k * NT);
    }
}

extern "C" void kernel_launch(void* const* d_in, const int* in_sizes, int n_in,
                              void* d_out, int out_size, void* d_ws, size_t ws_size,
                              hipStream_t stream) {
    const float* x     = (const float*)d_in[0];
    const float* gamma = (const float*)d_in[1];
    const float* beta  = (const float*)d_in[2];
    const void*  mask  = d_in[3];
    float* out = (float*)d_out;

    float* mg = (float*)d_ws;                      // Fn floats       (32 KB)
    unsigned* lwpk = (unsigned*)(mg + Fn);         // 256 uint32      (1 KB)
    float2* stats = (float2*)(lwpk + NT);          // Bn float2       (32 KB)

    prep_kernel<<<16, NT, 0, stream>>>(mask, gamma, lwpk, mg);
    stats_kernel<<<Bn / 4, NT, 0, stream>>>(x, lwpk, stats);
    apply_kernel<<<Bn, NT, 0, stream>>>(x, mg, beta, stats, out);
}

// Round 7
// 252.770 us; speedup vs baseline: 1.0197x; 1.0197x over previous
//
#include <hip/hip_runtime.h>

// DropNorm: B=4096 rows, F=8192 features, fp32.
//   n = F/2; mu = sum(x*m)/n; sigma2 = sum(((x-mu)*m)^2)/(n-1)
//   out = gamma*m*(x-mu)*rsqrt(sigma2^2 + 1e-4) + beta   [sigma2 SQUARED: quirk]
//
// R10: R8 DMA skeleton + half-row tiles (2x occupancy) + NORMAL stores.
//   R9 post-mortem: two-pass split = 94us combined vs 83 fused -> L3 carry
//   failed; reverted. Ledger: 6 structures all ~80us/2.4-3.2 TB/s, but m146
//   RMSNorm (same row dependency) does 4.89 TB/s on this chip -> structure
//   is not the ceiling. Constants across ALL slow attempts, absent from all
//   fast references: (a) nontemporal stores (never ablated; fill/copy/m146
//   use normal stores), (b) <=8-12 waves/CU during read phases (BW tracked
//   occupancy: 18%->2.44, 38%->3.09 TB/s). Fix both:
//     - 2 x 16KB half-row LDS buffers (33KB) -> 4 blocks/CU, 16 waves/CU.
//     - plain stores through L2 (the 6.8 TB/s fill path).
//     - counted vmcnt pipeline kept: per row, apply(prev half)->DMA(next
//       half)->stores, then vmcnt(12)/vmcnt(4) acc, reduce, RAW s_barrier
//       (lgkm-only). Buffers wave-quartered; partials parity ping-pong.
//   Tripwires: WRITE ~131MB & VGPR<=128 (no spill); Occupancy ~40-50%.

constexpr int Bn = 4096;
constexpr int Fn = 8192;
constexpr int NT = 256;           // threads per block
constexpr int RPB = 4;            // rows per block -> grid 1024
constexpr int HC = Fn / 2 / (NT * 4); // 4 f4 chunks per thread per half-row

typedef float f4 __attribute__((ext_vector_type(4)));

#define EPSV 1e-4f

__device__ __forceinline__ void cp16(const void* g, void* l) {
    // async global->LDS DMA, 16B/lane; LDS dest = wave-uniform base + lane*16
    __builtin_amdgcn_global_load_lds(
        (const __attribute__((address_space(1))) void*)g,
        (__attribute__((address_space(3))) void*)l, 16, 0, 0);
}

__device__ inline int nzbytes(unsigned v) {
    return ((v & 0x000000ffu) != 0) + ((v & 0x0000ff00u) != 0) +
           ((v & 0x00ff0000u) != 0) + ((v & 0xff000000u) != 0);
}

// Prep: detect mask storage layout (uint8 bool vs int32), then materialize
//   mg[j]    = mask ? gamma[j] : 0.0                    (Fn floats)
//   bitpk[t] = packed mask bits for thread t:
//              bit (h*16 + 4k + j) = mask[h*Fn/2 + 4*(t + k*NT) + j]
// Detection: count nonzero among the first Fn BYTES. uint8 layout -> exactly
// Fn/2 = 4096; int32 layout -> those bytes span only 2048 ints -> count <= 2048.
__global__ __launch_bounds__(NT) void prep_kernel(const void* __restrict__ mask_raw,
                                                  const float* __restrict__ gamma,
                                                  unsigned* __restrict__ bitpk,
                                                  float* __restrict__ mg) {
    const unsigned char* mb = (const unsigned char*)mask_raw;
    const int* mi = (const int*)mask_raw;
    const uint4* mv = (const uint4*)mask_raw;
    const int tid = threadIdx.x;

    int cnt = 0;
#pragma unroll
    for (int k = 0; k < Fn / 16 / NT; ++k) {   // 2 iterations
        const uint4 w = mv[tid + k * NT];
        cnt += nzbytes(w.x) + nzbytes(w.y) + nzbytes(w.z) + nzbytes(w.w);
    }
    for (int off = 32; off > 0; off >>= 1) cnt += __shfl_down(cnt, off, 64);

    __shared__ int wc[NT / 64];
    __shared__ int flag;
    if ((tid & 63) == 0) wc[tid >> 6] = cnt;
    __syncthreads();
    if (tid == 0) {
        int total = wc[0] + wc[1] + wc[2] + wc[3];
        flag = (total == Fn / 2) ? 1 : 0;   // 1 = uint8 layout, 0 = int32 layout
    }
    __syncthreads();
    const bool u8 = (flag != 0);

    const int per_block = Fn / gridDim.x;
    const int base = blockIdx.x * per_block;
    for (int j = base + tid; j < base + per_block; j += NT) {
        const bool on = u8 ? (mb[j] != 0) : (mi[j] != 0);
        mg[j] = on ? gamma[j] : 0.0f;
    }

    if (blockIdx.x == 0) {
        unsigned w = 0;
#pragma unroll
        for (int h = 0; h < 2; ++h) {
#pragma unroll
            for (int k = 0; k < HC; ++k) {
#pragma unroll
                for (int j = 0; j < 4; ++j) {
                    const int f = h * (Fn / 2) + 4 * (tid + k * NT) + j;
                    const bool on = u8 ? (mb[f] != 0) : (mi[f] != 0);
                    w |= (on ? 1u : 0u) << (h * 16 + 4 * k + j);
                }
            }
        }
        bitpk[tid] = w;
    }
}

// DMA half H of row (row0+RI) into lbuf[H]. Dest is wave-uniform; each
// wave fills only its own quarter (reads are wave-local too -> no barrier).
#define DMA_HALF(H, RI)                                                        \
    {                                                                          \
        const f4* __restrict__ xs =                                            \
            (const f4*)(x + (size_t)(row0 + (RI)) * Fn + (H) * (Fn / 2));      \
        _Pragma("unroll")                                                      \
        for (int k = 0; k < HC; ++k)                                           \
            cp16(xs + tid + k * NT, &lbuf[H][(wid << 6) + k * NT]);            \
        __builtin_amdgcn_sched_barrier(0);                                     \
    }

// Apply half H of row RO (data in lbuf[H]); if PF, DMA half H of row RN
// into the just-read buffer BEFORE issuing the stores (keeps vmcnt FIFO =
// D then S; ds_reads are pinned above the DMA by sched_barrier).
#define APPLY_HALF(H, RO, PF, RN)                                              \
    {                                                                          \
        f4 xv[HC];                                                             \
        _Pragma("unroll")                                                      \
        for (int k = 0; k < HC; ++k) xv[k] = lbuf[H][tid + k * NT];            \
        __builtin_amdgcn_sched_barrier(0);                                     \
        if (PF) DMA_HALF(H, RN)                                                \
        f4* __restrict__ o4 =                                                  \
            (f4*)(out + (size_t)(row0 + (RO)) * Fn + (H) * (Fn / 2));          \
        _Pragma("unroll")                                                      \
        for (int k = 0; k < HC; ++k) {                                         \
            const f4 g = gv[(H) * HC + k], b = bv[(H) * HC + k];               \
            f4 o;                                                              \
            o.x = g.x * (xv[k].x - mu) * inv + b.x;                            \
            o.y = g.y * (xv[k].y - mu) * inv + b.y;                            \
            o.z = g.z * (xv[k].z - mu) * inv + b.z;                            \
            o.w = g.w * (xv[k].w - mu) * inv + b.w;                            \
            o4[tid + k * NT] = o;            /* NORMAL store (NT ablated) */   \
        }                                                                      \
        __builtin_amdgcn_sched_barrier(0);                                     \
    }

#define ACC_HALF(H)                                                            \
    {                                                                          \
        _Pragma("unroll")                                                      \
        for (int k = 0; k < HC; ++k) {                                         \
            const f4 v = lbuf[H][tid + k * NT];                                \
            const float a0 = ((mbits >> ((H) * 16 + 4 * k + 0)) & 1u) ? v.x : 0.f; \
            const float a1 = ((mbits >> ((H) * 16 + 4 * k + 1)) & 1u) ? v.y : 0.f; \
            const float a2 = ((mbits >> ((H) * 16 + 4 * k + 2)) & 1u) ? v.z : 0.f; \
            const float a3 = ((mbits >> ((H) * 16 + 4 * k + 3)) & 1u) ? v.w : 0.f; \
            s  += (a0 + a1) + (a2 + a3);                                       \
            ss += (a0 * a0 + a1 * a1) + (a2 * a2 + a3 * a3);                   \
        }                                                                      \
    }

#define REDUCE(P)                                                              \
    {                                                                          \
        for (int off = 32; off > 0; off >>= 1) {                               \
            s  += __shfl_xor(s, off, 64);                                      \
            ss += __shfl_xor(ss, off, 64);                                     \
        }                                                                      \
        if ((tid & 63) == 0) { rs[P][wid] = s; rss[P][wid] = ss; }             \
        asm volatile("s_waitcnt lgkmcnt(0)" ::: "memory");                     \
        __builtin_amdgcn_s_barrier(); /* RAW: DMAs stay in flight */           \
    }

#define MUINV(P)                                                               \
    const float S  = (rs[P][0] + rs[P][1]) + (rs[P][2] + rs[P][3]);            \
    const float SS = (rss[P][0] + rss[P][1]) + (rss[P][2] + rss[P][3]);        \
    const float mu = S / nf;                                                   \
    const float sigma2 = (SS - nf * mu * mu) / (nf - 1.0f);                    \
    const float inv = rsqrtf(sigma2 * sigma2 + EPSV); /* quirk: sigma2^2 */

// Steady-state vmcnt FIFO per row: D0(4) S0(4) D1(4) S1(4).
//   vmcnt(12): D0 retired, stores+D1 may fly.  vmcnt(4): D1 retired, S1 flies.
#define BODY(R)                                                                \
    {                                                                          \
        MUINV((R - 1) & 1)                                                     \
        APPLY_HALF(0, R - 1, true, R)                                          \
        APPLY_HALF(1, R - 1, true, R)                                          \
        float s = 0.f, ss = 0.f;                                               \
        asm volatile("s_waitcnt vmcnt(12)" ::: "memory");                      \
        ACC_HALF(0)                                                            \
        asm volatile("s_waitcnt vmcnt(4)" ::: "memory");                       \
        ACC_HALF(1)                                                            \
        REDUCE(R & 1)                                                          \
    }

__global__ __launch_bounds__(NT, 4) void dropnorm_kernel(const float* __restrict__ x,
                                                         const unsigned* __restrict__ bitpk,
                                                         const float* __restrict__ mg,
                                                         const float* __restrict__ beta,
                                                         float* __restrict__ out) {
    __shared__ f4 lbuf[2][Fn / 8];                 // 2 x 16 KB half-row buffers
    __shared__ float rs[2][NT / 64], rss[2][NT / 64];

    const int tid = threadIdx.x;
    const int wid = tid >> 6;
    const int row0 = blockIdx.x * RPB;
    const float nf = (float)(Fn / 2);

    const f4* __restrict__ g4 = (const f4*)mg;
    const f4* __restrict__ b4 = (const f4*)beta;
    const unsigned mbits = bitpk[tid];

    // loop-invariant params hoisted once (64 VGPR; L2-hot)
    f4 gv[2 * HC], bv[2 * HC];
#pragma unroll
    for (int h = 0; h < 2; ++h)
#pragma unroll
        for (int k = 0; k < HC; ++k) {
            gv[h * HC + k] = g4[h * (Fn / 8) + tid + k * NT];
            bv[h * HC + k] = b4[h * (Fn / 8) + tid + k * NT];
        }

    // prologue: row 0, both halves
    DMA_HALF(0, 0)
    DMA_HALF(1, 0)
    {
        float s = 0.f, ss = 0.f;
        asm volatile("s_waitcnt vmcnt(4)" ::: "memory");  // h0 landed
        ACC_HALF(0)
        asm volatile("s_waitcnt vmcnt(0)" ::: "memory");  // h1 landed (no stores yet)
        ACC_HALF(1)
        REDUCE(0)
    }

    BODY(1)
    BODY(2)
    BODY(3)

    // epilogue: apply last row, no prefetch
    {
        MUINV(RPB & 1 ? 0 : 1)  // (RPB-1)&1 == 1 for RPB=4
        APPLY_HALF(0, RPB - 1, false, 0)
        APPLY_HALF(1, RPB - 1, false, 0)
    }
}

extern "C" void kernel_launch(void* const* d_in, const int* in_sizes, int n_in,
                              void* d_out, int out_size, void* d_ws, size_t ws_size,
                              hipStream_t stream) {
    const float* x     = (const float*)d_in[0];
    const float* gamma = (const float*)d_in[1];
    const float* beta  = (const float*)d_in[2];
    const void*  mask  = d_in[3];
    float* out = (float*)d_out;

    float* mg = (float*)d_ws;                      // Fn floats
    unsigned* bitpk = (unsigned*)(mg + Fn);        // NT uint32

    prep_kernel<<<16, NT, 0, stream>>>(mask, gamma, bitpk, mg);
    dropnorm_kernel<<<Bn / RPB, NT, 0, stream>>>(x, bitpk, mg, beta, out);
}